// Round 8
// baseline (960.970 us; speedup 1.0000x reference)
//
#include <hip/hip_runtime.h>
#include <hip/hip_bf16.h>
#include <math.h>
#include <stdint.h>

#define D 128

typedef unsigned short u16;
typedef unsigned int u32;
typedef __attribute__((ext_vector_type(8))) short bf16x8;
typedef __attribute__((ext_vector_type(4))) float f32x4;
typedef __attribute__((ext_vector_type(4))) unsigned short u16x4;

// ws layout (u16 units):
//  We1F [32768] @ 0       : K=256 B/A-frag layout (A-op for edge L1, symmetric)
//  Wn1F [32768] @ 32768   : K=256 B-frag layout (node L1)
//  Wn2F [16384] @ 65536   : K=128 B-frag layout (node L2)
//  WpE2 [16384] @ 81920   : paired-K16 A-frag layout (edge L2, transposed chain)
//  WpC1 [16384] @ 98304   : paired-K16 A-frag layout (edge C1)
//  We1r [128 f32] @114688
//  aggb [N*D bf16] @131072
#define WE1F_OFF 0
#define WN1F_OFF 32768
#define WN2F_OFF 65536
#define WPE2_OFF 81920
#define WPC1_OFF 98304
#define WE1R_OFF 114688
#define AGG_OFF  131072

__device__ __forceinline__ float silu_f(float x) {
    return x / (1.0f + __expf(-x));
}
__device__ __forceinline__ u16 f2bf(float x) {
    union { float f; unsigned int u; } v; v.f = x;
    unsigned int r = v.u + 0x7fffu + ((v.u >> 16) & 1u);
    return (u16)(r >> 16);
}
__device__ __forceinline__ float bf2f(u16 u) {
    union { unsigned int u; float f; } v; v.u = ((unsigned int)u) << 16; return v.f;
}
__device__ __forceinline__ u32 pk2bf(float a, float b) {
    union { __hip_bfloat162 v; u32 u; } u;
    u.v = __float22bfloat162_rn(make_float2(a, b));
    return u.u;
}
__device__ __forceinline__ void pk_agg_add(u16* addr, u32 packed) {
    asm volatile("global_atomic_pk_add_bf16 %0, %1, off"
                 :: "v"(addr), "v"(packed) : "memory");
}
union pk8 { u32 u[4]; bf16x8 v; };

// ---------------- prep + init (fused) ----------------
// ZA=1: zero bf16 agg in ws. ZA=0: zero fp32 agg (= out h region).
template<int ZA>
__global__ __launch_bounds__(256) void egnn_prep_init(
    const float* __restrict__ We1, const float* __restrict__ We2,
    const float* __restrict__ Wc1, const float* __restrict__ Wn1,
    const float* __restrict__ Wn2, u16* __restrict__ ws,
    const float* __restrict__ pos, float* __restrict__ out, int N)
{
    int i = blockIdx.x * blockDim.x + threadIdx.x;   // grid = 65536 threads
    int stride = gridDim.x * blockDim.x;

    if (i < 32768) {   // K=256 frag layout: k=kk*32+(l>>4)*8+j, n=nt*16+(l&15)
        int j = i & 7, l = (i >> 3) & 63, kk = (i >> 9) & 7, nt = i >> 12;
        int k = kk * 32 + (l >> 4) * 8 + j;
        int n = nt * 16 + (l & 15);
        ws[WE1F_OFF + i] = f2bf(We1[k * D + n]);
        ws[WN1F_OFF + i] = f2bf(Wn1[k * D + n]);
    }
    if (i < 16384) {
        int j = i & 7, l = (i >> 3) & 63;
        {   // node L2: K=128 B-frag: k=kk*32+(l>>4)*8+j
            int kk = (i >> 9) & 3, nt = i >> 11;
            int k = kk * 32 + (l >> 4) * 8 + j;
            int n = nt * 16 + (l & 15);
            ws[WN2F_OFF + i] = f2bf(Wn2[k * D + n]);
        }
        {   // edge L2/C1: paired-K16 A-frag: two 16-row slabs per K=32 MFMA
            // k = s*32 + (j>>2)*16 + (l>>4)*4 + (j&3), n = nt*16 + (l&15)
            int s = (i >> 9) & 3, nt = i >> 11;
            int k = s * 32 + ((j >> 2) * 16) + ((l >> 4) * 4) + (j & 3);
            int n = nt * 16 + (l & 15);
            ws[WPE2_OFF + i] = f2bf(We2[k * D + n]);
            ws[WPC1_OFF + i] = f2bf(Wc1[k * D + n]);
        }
    }
    if (i < 128) ((float*)(ws + WE1R_OFF))[i] = We1[256 * D + i];

    // pos -> pos_out
    for (int j = i; j < 3 * N; j += stride) out[(size_t)N * D + j] = pos[j];
    // zero agg
    if (ZA) {
        uint4* agg4 = (uint4*)(ws + AGG_OFF);
        int nagg = N * D / 8;
        for (int j = i; j < nagg; j += stride) agg4[j] = make_uint4(0, 0, 0, 0);
    } else {
        for (int j = i; j < N * D; j += stride) out[j] = 0.0f;
    }
}

// ---------------- transposed fused edge kernel ----------------
// 4 waves/block, 16 edges/wave (64/block). Each wave computes its edges'
// whole chain in registers: L1 (K=256, X direct-gathered into B-frags),
// L2/C1 (K=128 via paired-K16 frags), C2 dot, then pos + agg atomics.
// One barrier total (edge setup).
template<int BA>
__global__ __launch_bounds__(256, 4) void egnn_edge_t(
    const float* __restrict__ h, const float* __restrict__ pos,
    const int* __restrict__ eidx,
    const u16* __restrict__ We1F, const float* __restrict__ We1r,
    const float* __restrict__ be1,
    const u16* __restrict__ WpE2, const float* __restrict__ be2,
    const u16* __restrict__ WpC1, const float* __restrict__ bc1,
    const float* __restrict__ Wc2,
    u16* __restrict__ aggb, float* __restrict__ aggf,
    float* __restrict__ pos_out, int E)
{
    __shared__ int erow[64], ecol[64];
    __shared__ float ediff[64][3], edist[64];

    const int tid = threadIdx.x;
    const int w = tid >> 6, l = tid & 63;
    const int q = l >> 4, el = l & 15;
    const int e0 = blockIdx.x * 64;
    const int e_loc = w * 16 + el;
    const int ge = e0 + e_loc;

    if (tid < 64) {
        int e = e0 + tid;
        int r = 0, c = 0;
        if (e < E) { r = eidx[e]; c = eidx[E + e]; }
        erow[tid] = r; ecol[tid] = c;
        float dx = pos[r*3+0] - pos[c*3+0];
        float dy = pos[r*3+1] - pos[c*3+1];
        float dz = pos[r*3+2] - pos[c*3+2];
        float dd = fmaxf(sqrtf(dx*dx + dy*dy + dz*dz), 1e-6f);
        ediff[tid][0] = dx; ediff[tid][1] = dy; ediff[tid][2] = dz;
        edist[tid] = dd;
    }
    __syncthreads();

    const int nr = erow[e_loc], nc = ecol[e_loc];
    const float de = edist[e_loc];

    // ---- gather X = [h[row] | h[col]] directly into B-op frags ----
    // lane (e=el, q): frag kk holds X[e][kk*32 + q*8 .. +8] as bf16x8
    bf16x8 xf[8];
    #pragma unroll
    for (int kk = 0; kk < 8; ++kk) {
        const float* src = (kk < 4)
            ? (h + (size_t)nr * D + kk * 32 + q * 8)
            : (h + (size_t)nc * D + (kk - 4) * 32 + q * 8);
        float4 v0 = *(const float4*)src;
        float4 v1 = *(const float4*)(src + 4);
        pk8 b;
        b.u[0] = pk2bf(v0.x, v0.y);
        b.u[1] = pk2bf(v0.z, v0.w);
        b.u[2] = pk2bf(v1.x, v1.y);
        b.u[3] = pk2bf(v1.z, v1.w);
        xf[kk] = b.v;
    }

    // ---- L1: T1^T = We1^T(A) . X^T(B), K=256; dist column folded into init ----
    // output: lane holds col e=el, rows n1 = nt*16 + q*4 + rg
    u32 t1[8][2];
    #pragma unroll
    for (int nt = 0; nt < 8; ++nt) {
        float4 bv = *(const float4*)&be1[nt*16 + q*4];
        float4 wv = *(const float4*)&We1r[nt*16 + q*4];
        f32x4 c;
        c[0] = fmaf(de, wv.x, bv.x);
        c[1] = fmaf(de, wv.y, bv.y);
        c[2] = fmaf(de, wv.z, bv.z);
        c[3] = fmaf(de, wv.w, bv.w);
        #pragma unroll
        for (int kk = 0; kk < 8; ++kk) {
            bf16x8 a = *(const bf16x8*)&We1F[((nt*8 + kk)*64 + l)*8];
            c = __builtin_amdgcn_mfma_f32_16x16x32_bf16(a, xf[kk], c, 0, 0, 0);
        }
        t1[nt][0] = pk2bf(silu_f(c[0]), silu_f(c[1]));
        t1[nt][1] = pk2bf(silu_f(c[2]), silu_f(c[3]));
    }

    // ---- L2: M^T = We2^T(A) . T1^T(B), K=128 via 4 paired-K16 MFMAs ----
    u32 mg[8][2];
    #pragma unroll
    for (int nt = 0; nt < 8; ++nt) {
        float4 bv = *(const float4*)&be2[nt*16 + q*4];
        f32x4 c = { bv.x, bv.y, bv.z, bv.w };
        #pragma unroll
        for (int s = 0; s < 4; ++s) {
            bf16x8 a = *(const bf16x8*)&WpE2[((nt*4 + s)*64 + l)*8];
            pk8 b;
            b.u[0] = t1[2*s][0];   b.u[1] = t1[2*s][1];
            b.u[2] = t1[2*s+1][0]; b.u[3] = t1[2*s+1][1];
            c = __builtin_amdgcn_mfma_f32_16x16x32_bf16(a, b.v, c, 0, 0, 0);
        }
        mg[nt][0] = pk2bf(silu_f(c[0]), silu_f(c[1]));
        mg[nt][1] = pk2bf(silu_f(c[2]), silu_f(c[3]));
    }

    // ---- C1 + C2: S^T = Wc1^T(A) . M^T(B); p = S[e] . Wc2 (f32, no cvt) ----
    float p = 0.f;
    #pragma unroll
    for (int nt = 0; nt < 8; ++nt) {
        float4 bv = *(const float4*)&bc1[nt*16 + q*4];
        f32x4 c = { bv.x, bv.y, bv.z, bv.w };
        #pragma unroll
        for (int s = 0; s < 4; ++s) {
            bf16x8 a = *(const bf16x8*)&WpC1[((nt*4 + s)*64 + l)*8];
            pk8 b;
            b.u[0] = mg[2*s][0];   b.u[1] = mg[2*s][1];
            b.u[2] = mg[2*s+1][0]; b.u[3] = mg[2*s+1][1];
            c = __builtin_amdgcn_mfma_f32_16x16x32_bf16(a, b.v, c, 0, 0, 0);
        }
        float4 wc = *(const float4*)&Wc2[nt*16 + q*4];
        p += silu_f(c[0]) * wc.x + silu_f(c[1]) * wc.y
           + silu_f(c[2]) * wc.z + silu_f(c[3]) * wc.w;
    }
    p += __shfl_xor(p, 16);
    p += __shfl_xor(p, 32);

    // ---- pos scatter: lanes q=0,1,2 handle components x,y,z ----
    if (ge < E && q < 3) {
        float cw = fminf(1.0f, fmaxf(-1.0f, p));
        float s = cw / de;
        atomicAdd(&pos_out[nr*3 + q], ediff[e_loc][q] * s);
    }

    // ---- agg scatter: msg^T already per-lane; pk atomics on (n, n+1) pairs ----
    if (ge < E) {
        if (BA) {
            #pragma unroll
            for (int nt = 0; nt < 8; ++nt) {
                u16* base = aggb + (size_t)nr * D + nt*16 + q*4;
                pk_agg_add(base,     mg[nt][0]);
                pk_agg_add(base + 2, mg[nt][1]);
            }
        } else {
            #pragma unroll
            for (int nt = 0; nt < 8; ++nt) {
                float* base = aggf + (size_t)nr * D + nt*16 + q*4;
                atomicAdd(base + 0, bf2f((u16)mg[nt][0]));
                atomicAdd(base + 1, bf2f((u16)(mg[nt][0] >> 16)));
                atomicAdd(base + 2, bf2f((u16)mg[nt][1]));
                atomicAdd(base + 3, bf2f((u16)(mg[nt][1] >> 16)));
            }
        }
    }
}

// ---------------- node kernel: h_out = h + MLP([h|agg]) (R5 structure) ----------------
template<int BA>
__global__ __launch_bounds__(256, 4) void egnn_node_mfma(
    const float* __restrict__ h,
    const u16* __restrict__ aggb, const float* __restrict__ aggf,
    const u16* __restrict__ Wn1F, const float* __restrict__ bn1,
    const u16* __restrict__ Wn2F, const float* __restrict__ bn2,
    float* __restrict__ out, int N)
{
    __shared__ u16 A[64][264];

    const int tid = threadIdx.x;
    const int w = tid >> 6, l = tid & 63;
    const int q = l >> 4, m = l & 15;
    const int n0 = blockIdx.x * 64;

    bf16x8 B1[2][8];
    #pragma unroll
    for (int t2 = 0; t2 < 2; ++t2)
        #pragma unroll
        for (int kk = 0; kk < 8; ++kk)
            B1[t2][kk] = *(const bf16x8*)&Wn1F[(((2*w + t2)*8 + kk)*64 + l)*8];

    // gather [h | agg] -> bf16 LDS
    #pragma unroll
    for (int p = 0; p < 16; ++p) {
        int nl = p * 4 + w;
        int node = n0 + nl; if (node >= N) node = N - 1;
        if (l < 32) {
            int f0 = (l & 31) * 4;
            float4 v = *(const float4*)(h + (size_t)node * D + f0);
            uint2 pk; pk.x = pk2bf(v.x, v.y); pk.y = pk2bf(v.z, v.w);
            *(uint2*)&A[nl][f0] = pk;
        } else if (BA) {
            int f0 = (l & 31) * 4;
            u16x4 v = *(const u16x4*)&aggb[(size_t)node * D + f0];
            *(u16x4*)&A[nl][128 + f0] = v;
        } else {
            int f0 = (l & 31) * 4;
            float4 v = *(const float4*)(aggf + (size_t)node * D + f0);
            uint2 pk; pk.x = pk2bf(v.x, v.y); pk.y = pk2bf(v.z, v.w);
            *(uint2*)&A[nl][128 + f0] = pk;
        }
    }
    __syncthreads();

    // ---- node layer 1: hold in regs, then overlay T onto agg half ----
    u32 hold[4][2][2];
    {
        float b0[2];
        #pragma unroll
        for (int t2 = 0; t2 < 2; ++t2) b0[t2] = bn1[(2*w + t2)*16 + m];
        #pragma unroll
        for (int mt = 0; mt < 4; ++mt) {
            bf16x8 a[8];
            #pragma unroll
            for (int kk = 0; kk < 8; ++kk)
                a[kk] = *(const bf16x8*)&A[mt*16 + m][kk*32 + q*8];
            #pragma unroll
            for (int t2 = 0; t2 < 2; ++t2) {
                f32x4 c = { b0[t2], b0[t2], b0[t2], b0[t2] };
                #pragma unroll
                for (int kk = 0; kk < 8; ++kk)
                    c = __builtin_amdgcn_mfma_f32_16x16x32_bf16(a[kk], B1[t2][kk], c, 0, 0, 0);
                hold[mt][t2][0] = pk2bf(silu_f(c[0]), silu_f(c[1]));
                hold[mt][t2][1] = pk2bf(silu_f(c[2]), silu_f(c[3]));
            }
        }
    }
    __syncthreads();

    #pragma unroll
    for (int mt = 0; mt < 4; ++mt)
        #pragma unroll
        for (int t2 = 0; t2 < 2; ++t2) {
            int n = 128 + (2*w + t2)*16 + m;
            int rb = mt*16 + q*4;
            u32 h0 = hold[mt][t2][0], h1 = hold[mt][t2][1];
            A[rb + 0][n] = (u16)h0;
            A[rb + 1][n] = (u16)(h0 >> 16);
            A[rb + 2][n] = (u16)h1;
            A[rb + 3][n] = (u16)(h1 >> 16);
        }
    __syncthreads();

    // ---- node layer 2 + residual (h from LDS bf16) ----
    {
        bf16x8 Bf[2][4];
        #pragma unroll
        for (int t2 = 0; t2 < 2; ++t2)
            #pragma unroll
            for (int kk = 0; kk < 4; ++kk)
                Bf[t2][kk] = *(const bf16x8*)&Wn2F[(((2*w + t2)*4 + kk)*64 + l)*8];
        float b0[2];
        #pragma unroll
        for (int t2 = 0; t2 < 2; ++t2) b0[t2] = bn2[(2*w + t2)*16 + m];
        #pragma unroll
        for (int mt = 0; mt < 4; ++mt) {
            bf16x8 a[4];
            #pragma unroll
            for (int kk = 0; kk < 4; ++kk)
                a[kk] = *(const bf16x8*)&A[mt*16 + m][128 + kk*32 + q*8];
            #pragma unroll
            for (int t2 = 0; t2 < 2; ++t2) {
                f32x4 c = { b0[t2], b0[t2], b0[t2], b0[t2] };
                #pragma unroll
                for (int kk = 0; kk < 4; ++kk)
                    c = __builtin_amdgcn_mfma_f32_16x16x32_bf16(a[kk], Bf[t2][kk], c, 0, 0, 0);
                int n = (2*w + t2)*16 + m;
                #pragma unroll
                for (int rg = 0; rg < 4; ++rg) {
                    int node = n0 + mt*16 + q*4 + rg;
                    if (node < N)
                        out[(size_t)node * D + n] =
                            bf2f(A[mt*16 + q*4 + rg][n]) + c[rg];
                }
            }
        }
    }
}

extern "C" void kernel_launch(void* const* d_in, const int* in_sizes, int n_in,
                              void* d_out, int out_size, void* d_ws, size_t ws_size,
                              hipStream_t stream)
{
    const float* h   = (const float*)d_in[0];
    const float* pos = (const float*)d_in[1];
    const int*   eidx= (const int*)d_in[2];
    const float* We1 = (const float*)d_in[3];
    const float* be1 = (const float*)d_in[4];
    const float* We2 = (const float*)d_in[5];
    const float* be2 = (const float*)d_in[6];
    const float* Wn1 = (const float*)d_in[7];
    const float* bn1 = (const float*)d_in[8];
    const float* Wn2 = (const float*)d_in[9];
    const float* bn2 = (const float*)d_in[10];
    const float* Wc1 = (const float*)d_in[11];
    const float* bc1 = (const float*)d_in[12];
    const float* Wc2 = (const float*)d_in[13];

    const int N = in_sizes[0] / D;
    const int E = in_sizes[2] / 2;

    float* out     = (float*)d_out;
    float* pos_out = out + (size_t)N * D;

    u16* ws = (u16*)d_ws;
    const u16* We1F = ws + WE1F_OFF;
    const u16* Wn1F = ws + WN1F_OFF;
    const u16* Wn2F = ws + WN2F_OFF;
    const u16* WpE2 = ws + WPE2_OFF;
    const u16* WpC1 = ws + WPC1_OFF;
    const float* We1r = (const float*)(ws + WE1R_OFF);

    u16*   aggb = ws + AGG_OFF;
    float* aggf = out;   // fallback: fp32 agg in out h-region

    const size_t need = ((size_t)AGG_OFF + (size_t)N * D) * 2;
    const bool ba = ws_size >= need;

    if (ba) {
        egnn_prep_init<1><<<256, 256, 0, stream>>>(
            We1, We2, Wc1, Wn1, Wn2, ws, pos, out, N);
        egnn_edge_t<1><<<(E + 63) / 64, 256, 0, stream>>>(
            h, pos, eidx, We1F, We1r, be1, WpE2, be2, WpC1, bc1, Wc2,
            aggb, aggf, pos_out, E);
        egnn_node_mfma<1><<<(N + 63) / 64, 256, 0, stream>>>(
            h, aggb, aggf, Wn1F, bn1, Wn2F, bn2, out, N);
    } else {
        egnn_prep_init<0><<<256, 256, 0, stream>>>(
            We1, We2, Wc1, Wn1, Wn2, ws, pos, out, N);
        egnn_edge_t<0><<<(E + 63) / 64, 256, 0, stream>>>(
            h, pos, eidx, We1F, We1r, be1, WpE2, be2, WpC1, bc1, Wc2,
            aggb, aggf, pos_out, E);
        egnn_node_mfma<0><<<(N + 63) / 64, 256, 0, stream>>>(
            h, aggb, aggf, Wn1F, bn1, Wn2F, bn2, out, N);
    }
}